// Round 10
// baseline (363.039 us; speedup 1.0000x reference)
//
#include <hip/hip_runtime.h>
#include <hip/hip_bf16.h>
#include <stdint.h>

#define DIM   1024
#define ODIM  3072
#define MROWS 32768   // B(8) * N(4096)
#define RANK  8
#define BK    32

typedef unsigned short u16;
typedef __attribute__((ext_vector_type(8))) short short8;
typedef __attribute__((ext_vector_type(8))) unsigned short u16x8;
typedef __attribute__((ext_vector_type(4))) unsigned short u16x4;
typedef __attribute__((ext_vector_type(4))) float f32x4;

__device__ __forceinline__ u16 f2bf(float f) {
    uint32_t u = __float_as_uint(f);
    u += 0x7fffu + ((u >> 16) & 1u);   // RNE
    return (u16)(u >> 16);
}

__device__ __forceinline__ void gl2lds16(const void* g, void* l) {
    __builtin_amdgcn_global_load_lds(
        (const __attribute__((address_space(1))) void*)(uintptr_t)g,
        (__attribute__((address_space(3))) void*)(uint32_t)(uintptr_t)l,
        16, 0, 0);
}

#define BAR()    do { asm volatile("" ::: "memory"); __builtin_amdgcn_s_barrier(); asm volatile("" ::: "memory"); } while (0)
#define WAITV0() asm volatile("s_waitcnt vmcnt(0)" ::: "memory")
#define WAITL0() asm volatile("s_waitcnt lgkmcnt(0)" ::: "memory")

// ---------------- f32 -> bf16 conversion ----------------
__global__ __launch_bounds__(256) void k_convert(const float* __restrict__ src,
                                                 u16* __restrict__ dst, int n) {
    const int stride = gridDim.x * blockDim.x;
    for (int t = blockIdx.x * blockDim.x + threadIdx.x; t * 8 < n; t += stride) {
        const int i = t * 8;
        float4 a = *reinterpret_cast<const float4*>(src + i);
        float4 b = *reinterpret_cast<const float4*>(src + i + 4);
        u16x8 o;
        o[0] = f2bf(a.x); o[1] = f2bf(a.y); o[2] = f2bf(a.z); o[3] = f2bf(a.w);
        o[4] = f2bf(b.x); o[5] = f2bf(b.y); o[6] = f2bf(b.z); o[7] = f2bf(b.w);
        *reinterpret_cast<u16x8*>(dst + i) = o;
    }
}

// ---------------- Wmod[b] = W_slab + (A[idx_b] @ B[idx_b])^T, bf16 ----------------
__global__ __launch_bounds__(256) void k_build(const float* __restrict__ W,
                                               const float* __restrict__ Aq_pool,
                                               const float* __restrict__ Bq_pool,
                                               const float* __restrict__ Av_pool,
                                               const float* __restrict__ Bv_pool,
                                               const int* __restrict__ idx,
                                               u16* __restrict__ Wmq,
                                               u16* __restrict__ Wmv) {
    const int b  = blockIdx.x >> 7;
    const int s  = (blockIdx.x >> 6) & 1;
    const int og = blockIdx.x & 63;
    const int p  = idx[b];
    const float* A  = (s ? Av_pool : Aq_pool) + (size_t)p * DIM * RANK;
    const float* Bp = (s ? Bv_pool : Bq_pool) + (size_t)p * RANK * DIM;
    const float* Ws = W + (size_t)(s ? 2048 : 0) * DIM;
    u16* dst = (s ? Wmv : Wmq) + (size_t)b * DIM * DIM;

    const int t  = threadIdx.x;
    const int i0 = t * 4;
    float a[4][8];
    #pragma unroll
    for (int ii = 0; ii < 4; ++ii) {
        float4 a0 = reinterpret_cast<const float4*>(A + (size_t)(i0 + ii) * RANK)[0];
        float4 a1 = reinterpret_cast<const float4*>(A + (size_t)(i0 + ii) * RANK)[1];
        a[ii][0] = a0.x; a[ii][1] = a0.y; a[ii][2] = a0.z; a[ii][3] = a0.w;
        a[ii][4] = a1.x; a[ii][5] = a1.y; a[ii][6] = a1.z; a[ii][7] = a1.w;
    }
    for (int r = 0; r < 16; ++r) {
        const int o = og * 16 + r;
        float bv[8];
        #pragma unroll
        for (int rr = 0; rr < 8; ++rr) bv[rr] = Bp[(size_t)rr * DIM + o];
        float4 w = *reinterpret_cast<const float4*>(Ws + (size_t)o * DIM + i0);
        float v[4] = {w.x, w.y, w.z, w.w};
        u16x4 ov;
        #pragma unroll
        for (int ii = 0; ii < 4; ++ii) {
            float d = 0.f;
            #pragma unroll
            for (int rr = 0; rr < 8; ++rr) d += a[ii][rr] * bv[rr];
            ov[ii] = f2bf(v[ii] + d);
        }
        *reinterpret_cast<u16x4*>(dst + (size_t)o * DIM + i0) = ov;
    }
}

// ---------------- 128x128 4-wave double-buffered GEMM, 4 blocks/CU ----------------
// Rationale: K=1024 (16-32 tiles) + 393MB f32 epilogue make per-block overheads
// (prologue drain, per-tile vmcnt, epilogue stores) a large fraction; at
// 1 block/CU they serialize. 4 small blocks/CU (reg-capped 16 waves/CU) hide
// each other's stalls — the m97 mechanism. Per wave: 64x64 out, acc=64 regs.
// LDS: 2 buf x (A 128x32 + B 128x32) bf16 = 32 KiB static.
// Layout (R6-measured 0-conflict): matrix row r, 16B k-group gk -> LDS row
// r>>1 (128B), slot ((r&1)*4+gk)^((r>>1)&7). Stage via gl2lds16 linear dest +
// inverse-permuted global source (rule #21). Read axc: lr=lane&15, kg=lane>>4:
// (lr>>1)*64 + ((((lr&1)*4)+kg)^(lr>>1))*8  (2-way max = free, m136).
// Schedule/tile: 8 ds_read(buf p) | stage t+1 -> buf p^1 (4 gl2lds) | lgkm0 |
// prio1 16 MFMA prio0 | vmcnt(0) | BAR.  vmcnt distance = MFMA cluster; with
// L2-warm X/W (~200-400cyc) mostly covered; residue hidden by 3 other blocks.

__device__ __forceinline__ void stage(const u16* __restrict__ Xc,
                                      const u16* __restrict__ Bm,
                                      int m0, int nc, int tk,
                                      u16* buf, int wave, int lane) {
    const int q  = (lane & 7) ^ (lane >> 3);
    const int rl = (lane >> 3) * 2 + (q >> 2);      // row within 16-row slab
    const int gk = q & 3;                            // 16B k-group
    #pragma unroll
    for (int j = 0; j < 2; ++j) {
        const int row = wave * 32 + j * 16 + rl;
        gl2lds16(Xc + (size_t)(m0 + row) * DIM + tk + gk * 8,
                 buf + wave * 1024 + j * 512);
        gl2lds16(Bm + (size_t)(nc + row) * DIM + tk + gk * 8,
                 buf + 4096 + wave * 1024 + j * 512);
    }
}

__device__ __forceinline__ void tile_mfma(const u16* __restrict__ buf,
                                          int wr, int wc, int axc,
                                          f32x4 (&acc)[4][4]) {
    short8 a[4], b[4];
    #pragma unroll
    for (int f = 0; f < 4; ++f)
        a[f] = *reinterpret_cast<const short8*>(buf + wr * 2048 + f * 512 + axc);
    #pragma unroll
    for (int n = 0; n < 4; ++n)
        b[n] = *reinterpret_cast<const short8*>(buf + 4096 + wc * 2048 + n * 512 + axc);
    WAITL0();
    __builtin_amdgcn_s_setprio(1);
    #pragma unroll
    for (int f = 0; f < 4; ++f)
        #pragma unroll
        for (int n = 0; n < 4; ++n)
            acc[f][n] = __builtin_amdgcn_mfma_f32_16x16x32_bf16(a[f], b[n], acc[f][n], 0, 0, 0);
    __builtin_amdgcn_s_setprio(0);
}

__global__ __launch_bounds__(256, 4) void k_gemm(const u16* __restrict__ Xc,
                                                 const u16* __restrict__ Wk,
                                                 const u16* __restrict__ Wmq,
                                                 const u16* __restrict__ Wmv,
                                                 const float* __restrict__ bias,
                                                 float* __restrict__ out) {
    __shared__ u16 lds[2][8192];               // 32 KiB
    const int tid  = threadIdx.x;
    const int lane = tid & 63, wave = tid >> 6;
    const int wr = wave >> 1, wc = wave & 1;   // 2M x 2N wave grid, 64x64 each

    // bijective XCD swizzle (nwg=6144, 6144%8==0)
    const int orig = blockIdx.x;
    const int wg   = (orig & 7) * 768 + (orig >> 3);
    const int bn   = wg % 24;
    const int bm   = wg / 24;
    const int m0 = bm * 128, n0 = bn * 128;
    const int batch = m0 >> 12;

    const u16* Bmat;
    int nc;
    if (n0 < DIM)           { Bmat = Wmq + (size_t)batch * DIM * DIM; nc = n0; }
    else if (n0 < 2 * DIM)  { Bmat = Wk;                              nc = n0 - DIM; }
    else                    { Bmat = Wmv + (size_t)batch * DIM * DIM; nc = n0 - 2 * DIM; }

    const int lr  = lane & 15;
    const int axc = (lr >> 1) * 64 + ((((lr & 1) * 4) + (lane >> 4)) ^ (lr >> 1)) * 8;

    f32x4 acc[4][4] = {};

    // prologue: stage tile 0 into buf 0, drain
    stage(Xc, Bmat, m0, nc, 0, lds[0], wave, lane);
    WAITV0(); BAR();

    #pragma unroll 1
    for (int t = 0; t < 31; ++t) {
        stage(Xc, Bmat, m0, nc, (t + 1) * BK, lds[(t + 1) & 1], wave, lane);
        tile_mfma(lds[t & 1], wr, wc, axc, acc);
        WAITV0(); BAR();
    }
    // t = 31: no staging
    tile_mfma(lds[1], wr, wc, axc, acc);

    // ---------------- epilogue: bias + store ----------------
    const int cn = wc * 64 + (lane & 15);
    float bcol[4];
    #pragma unroll
    for (int n = 0; n < 4; ++n) bcol[n] = bias[n0 + cn + n * 16];
    #pragma unroll
    for (int f = 0; f < 4; ++f) {
        const int rb = m0 + wr * 64 + f * 16 + (lane >> 4) * 4;
        #pragma unroll
        for (int v = 0; v < 4; ++v) {
            const size_t row = (size_t)(rb + v);
            #pragma unroll
            for (int n = 0; n < 4; ++n)
                out[row * ODIM + (size_t)(n0 + cn + n * 16)] = acc[f][n][v] + bcol[n];
        }
    }
}

extern "C" void kernel_launch(void* const* d_in, const int* in_sizes, int n_in,
                              void* d_out, int out_size, void* d_ws, size_t ws_size,
                              hipStream_t stream) {
    const float* x      = (const float*)d_in[0];
    const float* weight = (const float*)d_in[1];
    const float* bias   = (const float*)d_in[2];
    const float* Aq     = (const float*)d_in[3];
    const float* Bq     = (const float*)d_in[4];
    const float* Av     = (const float*)d_in[5];
    const float* Bv     = (const float*)d_in[6];
    const int*   idx    = (const int*)d_in[7];
    float* out = (float*)d_out;

    // workspace: Xc(64MB) | Wk(2MB) | Wmq(16MB) | Wmv(16MB) = 98MB
    u16* Xc  = (u16*)d_ws;
    u16* Wk  = Xc + (size_t)MROWS * DIM;
    u16* Wmq = Wk + (size_t)DIM * DIM;
    u16* Wmv = Wmq + (size_t)8 * DIM * DIM;

    k_convert<<<2048, 256, 0, stream>>>(x, Xc, MROWS * DIM);
    k_convert<<<512, 256, 0, stream>>>(weight + (size_t)DIM * DIM, Wk, DIM * DIM);
    k_build<<<1024, 256, 0, stream>>>(weight, Aq, Bq, Av, Bv, idx, Wmq, Wmv);
    k_gemm<<<6144, 256, 0, stream>>>(Xc, Wk, Wmq, Wmv, bias, out);
}

// Round 11
// 328.685 us; speedup vs baseline: 1.1045x; 1.1045x over previous
//
#include <hip/hip_runtime.h>
#include <hip/hip_bf16.h>
#include <stdint.h>

#define DIM   1024
#define ODIM  3072
#define MROWS 32768   // B(8) * N(4096)
#define RANK  8
#define BK    32

typedef unsigned short u16;
typedef __attribute__((ext_vector_type(8))) short short8;
typedef __attribute__((ext_vector_type(8))) unsigned short u16x8;
typedef __attribute__((ext_vector_type(4))) unsigned short u16x4;
typedef __attribute__((ext_vector_type(16))) float f32x16;

__device__ __forceinline__ u16 f2bf(float f) {
    uint32_t u = __float_as_uint(f);
    u += 0x7fffu + ((u >> 16) & 1u);   // RNE
    return (u16)(u >> 16);
}

__device__ __forceinline__ void gl2lds16(const void* g, void* l) {
    __builtin_amdgcn_global_load_lds(
        (const __attribute__((address_space(1))) void*)(uintptr_t)g,
        (__attribute__((address_space(3))) void*)(uint32_t)(uintptr_t)l,
        16, 0, 0);
}

#define BAR()    do { asm volatile("" ::: "memory"); __builtin_amdgcn_s_barrier(); asm volatile("" ::: "memory"); } while (0)
#define WAITV3() asm volatile("s_waitcnt vmcnt(3)" ::: "memory")
#define WAITV0() asm volatile("s_waitcnt vmcnt(0)" ::: "memory")

// ---------------- f32 -> bf16 conversion ----------------
__global__ __launch_bounds__(256) void k_convert(const float* __restrict__ src,
                                                 u16* __restrict__ dst, int n) {
    const int stride = gridDim.x * blockDim.x;
    for (int t = blockIdx.x * blockDim.x + threadIdx.x; t * 8 < n; t += stride) {
        const int i = t * 8;
        float4 a = *reinterpret_cast<const float4*>(src + i);
        float4 b = *reinterpret_cast<const float4*>(src + i + 4);
        u16x8 o;
        o[0] = f2bf(a.x); o[1] = f2bf(a.y); o[2] = f2bf(a.z); o[3] = f2bf(a.w);
        o[4] = f2bf(b.x); o[5] = f2bf(b.y); o[6] = f2bf(b.z); o[7] = f2bf(b.w);
        *reinterpret_cast<u16x8*>(dst + i) = o;
    }
}

// ---------------- Wmod[b] = W_slab + (A[idx_b] @ B[idx_b])^T, bf16 ----------------
__global__ __launch_bounds__(256) void k_build(const float* __restrict__ W,
                                               const float* __restrict__ Aq_pool,
                                               const float* __restrict__ Bq_pool,
                                               const float* __restrict__ Av_pool,
                                               const float* __restrict__ Bv_pool,
                                               const int* __restrict__ idx,
                                               u16* __restrict__ Wmq,
                                               u16* __restrict__ Wmv) {
    const int b  = blockIdx.x >> 7;
    const int s  = (blockIdx.x >> 6) & 1;
    const int og = blockIdx.x & 63;
    const int p  = idx[b];
    const float* A  = (s ? Av_pool : Aq_pool) + (size_t)p * DIM * RANK;
    const float* Bp = (s ? Bv_pool : Bq_pool) + (size_t)p * RANK * DIM;
    const float* Ws = W + (size_t)(s ? 2048 : 0) * DIM;
    u16* dst = (s ? Wmv : Wmq) + (size_t)b * DIM * DIM;

    const int t  = threadIdx.x;
    const int i0 = t * 4;
    float a[4][8];
    #pragma unroll
    for (int ii = 0; ii < 4; ++ii) {
        float4 a0 = reinterpret_cast<const float4*>(A + (size_t)(i0 + ii) * RANK)[0];
        float4 a1 = reinterpret_cast<const float4*>(A + (size_t)(i0 + ii) * RANK)[1];
        a[ii][0] = a0.x; a[ii][1] = a0.y; a[ii][2] = a0.z; a[ii][3] = a0.w;
        a[ii][4] = a1.x; a[ii][5] = a1.y; a[ii][6] = a1.z; a[ii][7] = a1.w;
    }
    for (int r = 0; r < 16; ++r) {
        const int o = og * 16 + r;
        float bv[8];
        #pragma unroll
        for (int rr = 0; rr < 8; ++rr) bv[rr] = Bp[(size_t)rr * DIM + o];
        float4 w = *reinterpret_cast<const float4*>(Ws + (size_t)o * DIM + i0);
        float v[4] = {w.x, w.y, w.z, w.w};
        u16x4 ov;
        #pragma unroll
        for (int ii = 0; ii < 4; ++ii) {
            float d = 0.f;
            #pragma unroll
            for (int rr = 0; rr < 8; ++rr) d += a[ii][rr] * bv[rr];
            ov[ii] = f2bf(v[ii] + d);
        }
        *reinterpret_cast<u16x4*>(dst + (size_t)o * DIM + i0) = ov;
    }
}

// ---------------- 128x256 8-wave triple-buffered GEMM, 2 blocks/CU -------------
// 32x32x16 MFMA (2495 TF pipe, half issue slots of 16x16). Per wave 64x64
// (2x2 acc f32x16 = 64 regs). 8 waves = 2wr x 4wc. BK=32.
// LDS: 3 buf x (A 128x32 + B 256x32) bf16 = 72 KiB dyn -> 2 blocks/CU (144K),
// launch_bounds(512,4) -> 16 waves/CU; two independent barrier groups hide
// each other's stage/drain stalls (the m97 mechanism, without R10's L2 blowup:
// BN=256 keeps X re-read passes at 12, same fetch profile as R9).
// LDS layout (R6-measured 0-conflict): matrix row r, 16B k-group gk (0..3) ->
// LDS row r>>1 (128B), slot ((r&1)*4+gk)^((r>>1)&7). Stage = gl2lds16 linear
// dest + inverse-permuted global src (rule #21).
// Frag read (32x32x16): lane holds row lane&31, k=(lane>>5)*8 + ks*16 ->
// slot = ((lane&1)*4 + (lane>>5) + 2*ks) ^ (((lane&31)>>1)&7)  [bijective 0..7
// per 8-lane beat -> conflict-free].
// Schedule/tile t: stage(t+2, 3 loads/wave) | 8 ds_read | prio1 8 MFMA prio0 |
// vmcnt(3) retires tile t+1's loads (t+2 stays in flight — never drains) | BAR.
// Tail: t=30 vmcnt(0) (retire t31), t=31 no wait. All count-guaranteed.

__device__ __forceinline__ void stage(const u16* __restrict__ Xc,
                                      const u16* __restrict__ Bm,
                                      int m0, int nc, int tk,
                                      u16* buf, int wave, int lane) {
    const int q  = (lane & 7) ^ (lane >> 3);
    const int r  = (lane >> 3) * 2 + (q >> 2);      // row within 16-row slab
    const int gk = q & 3;                            // 16B k-group
    // A: wave owns 16 rows (1 load); dest rows wave*8..+8 linear
    gl2lds16(Xc + (size_t)(m0 + wave * 16 + r) * DIM + tk + gk * 8,
             buf + wave * 512);
    // B: wave owns 32 rows (2 loads)
    gl2lds16(Bm + (size_t)(nc + wave * 32 + r) * DIM + tk + gk * 8,
             buf + 4096 + wave * 1024);
    gl2lds16(Bm + (size_t)(nc + wave * 32 + 16 + r) * DIM + tk + gk * 8,
             buf + 4096 + wave * 1024 + 512);
}

__device__ __forceinline__ void tile_mfma(const u16* __restrict__ buf,
                                          int wr, int wc, int rl, int lo4, int kb,
                                          f32x16 (&acc)[2][2]) {
    short8 a[2][2], b[2][2];
    const int x7 = rl & 7;
    #pragma unroll
    for (int f = 0; f < 2; ++f)
        #pragma unroll
        for (int ks = 0; ks < 2; ++ks)
            a[f][ks] = *reinterpret_cast<const short8*>(
                buf + (wr * 32 + f * 16 + rl) * 64 + ((lo4 + kb + 2 * ks) ^ x7) * 8);
    #pragma unroll
    for (int n = 0; n < 2; ++n)
        #pragma unroll
        for (int ks = 0; ks < 2; ++ks)
            b[n][ks] = *reinterpret_cast<const short8*>(
                buf + 4096 + (wc * 32 + n * 16 + rl) * 64 + ((lo4 + kb + 2 * ks) ^ x7) * 8);
    __builtin_amdgcn_s_setprio(1);
    #pragma unroll
    for (int f = 0; f < 2; ++f)
        #pragma unroll
        for (int n = 0; n < 2; ++n)
            #pragma unroll
            for (int ks = 0; ks < 2; ++ks)
                acc[f][n] = __builtin_amdgcn_mfma_f32_32x32x16_bf16(
                    a[f][ks], b[n][ks], acc[f][n], 0, 0, 0);
    __builtin_amdgcn_s_setprio(0);
}

__global__ __launch_bounds__(512, 4) void k_gemm(const u16* __restrict__ Xc,
                                                 const u16* __restrict__ Wk,
                                                 const u16* __restrict__ Wmq,
                                                 const u16* __restrict__ Wmv,
                                                 const float* __restrict__ bias,
                                                 float* __restrict__ out) {
    extern __shared__ u16 lds[];               // 72 KiB: 3 x 12288 u16
    const int tid  = threadIdx.x;
    const int lane = tid & 63, wave = tid >> 6;
    const int wr = wave >> 2, wc = wave & 3;   // 2M x 4N wave grid, 64x64 each

    // bijective XCD swizzle (nwg=3072, 3072%8==0)
    const int orig = blockIdx.x;
    const int wg   = (orig & 7) * 384 + (orig >> 3);
    const int bn   = wg % 12;
    const int bm   = wg / 12;
    const int m0 = bm * 128, n0 = bn * 256;
    const int batch = m0 >> 12;

    const u16* Bmat;
    int nc;
    if (n0 < DIM)           { Bmat = Wmq + (size_t)batch * DIM * DIM; nc = n0; }
    else if (n0 < 2 * DIM)  { Bmat = Wk;                              nc = n0 - DIM; }
    else                    { Bmat = Wmv + (size_t)batch * DIM * DIM; nc = n0 - 2 * DIM; }

    const int rl  = (lane & 31) >> 1;
    const int lo4 = (lane & 1) * 4;
    const int kb  = lane >> 5;

    u16* p0 = lds;
    u16* p1 = lds + 12288;
    u16* p2 = lds + 24576;

    f32x16 acc[2][2] = {};

    // prologue: stage tiles 0,1; retire tile 0 by count
    stage(Xc, Bmat, m0, nc, 0,  p0, wave, lane);
    stage(Xc, Bmat, m0, nc, BK, p1, wave, lane);
    WAITV3(); BAR();

    #pragma unroll 1
    for (int t = 0; t < 30; ++t) {
        stage(Xc, Bmat, m0, nc, (t + 2) * BK, p2, wave, lane);
        tile_mfma(p0, wr, wc, rl, lo4, kb, acc);
        WAITV3(); BAR();               // retire tile t+1 (read next iter)
        u16* tmp = p0; p0 = p1; p1 = p2; p2 = tmp;
    }
    // t = 30: read p0 (tile 30), no stage; drain tile 31
    tile_mfma(p0, wr, wc, rl, lo4, kb, acc);
    WAITV0(); BAR();
    // t = 31: read p1
    tile_mfma(p1, wr, wc, rl, lo4, kb, acc);

    // ---------------- epilogue: bias + store ----------------
    // C/D (32x32): col = lane&31, row = (v&3) + 8*(v>>2) + 4*(lane>>5)
    const int cb = lane & 31;
    float bcol[2];
    #pragma unroll
    for (int n = 0; n < 2; ++n) bcol[n] = bias[n0 + wc * 64 + n * 32 + cb];
    #pragma unroll
    for (int f = 0; f < 2; ++f) {
        const int rbase = m0 + wr * 64 + f * 32 + 4 * kb;
        #pragma unroll
        for (int n = 0; n < 2; ++n) {
            const size_t col = (size_t)(n0 + wc * 64 + n * 32 + cb);
            #pragma unroll
            for (int v = 0; v < 16; ++v) {
                const size_t row = (size_t)(rbase + (v & 3) + 8 * (v >> 2));
                out[row * ODIM + col] = acc[f][n][v] + bcol[n];
            }
        }
    }
}

extern "C" void kernel_launch(void* const* d_in, const int* in_sizes, int n_in,
                              void* d_out, int out_size, void* d_ws, size_t ws_size,
                              hipStream_t stream) {
    const float* x      = (const float*)d_in[0];
    const float* weight = (const float*)d_in[1];
    const float* bias   = (const float*)d_in[2];
    const float* Aq     = (const float*)d_in[3];
    const float* Bq     = (const float*)d_in[4];
    const float* Av     = (const float*)d_in[5];
    const float* Bv     = (const float*)d_in[6];
    const int*   idx    = (const int*)d_in[7];
    float* out = (float*)d_out;

    // workspace: Xc(64MB) | Wk(2MB) | Wmq(16MB) | Wmv(16MB) = 98MB
    u16* Xc  = (u16*)d_ws;
    u16* Wk  = Xc + (size_t)MROWS * DIM;
    u16* Wmq = Wk + (size_t)DIM * DIM;
    u16* Wmv = Wmq + (size_t)8 * DIM * DIM;

    hipFuncSetAttribute(reinterpret_cast<const void*>(k_gemm),
                        hipFuncAttributeMaxDynamicSharedMemorySize, 73728);

    k_convert<<<2048, 256, 0, stream>>>(x, Xc, MROWS * DIM);
    k_convert<<<512, 256, 0, stream>>>(weight + (size_t)DIM * DIM, Wk, DIM * DIM);
    k_build<<<1024, 256, 0, stream>>>(weight, Aq, Bq, Av, Bv, idx, Wmq, Wmv);
    k_gemm<<<3072, 512, 73728, stream>>>(Xc, Wk, Wmq, Wmv, bias, out);
}

// Round 12
// 314.601 us; speedup vs baseline: 1.1540x; 1.0448x over previous
//
#include <hip/hip_runtime.h>
#include <hip/hip_bf16.h>
#include <stdint.h>

#define DIM   1024
#define ODIM  3072
#define MROWS 32768   // B(8) * N(4096)
#define RANK  8
#define BK    32

typedef unsigned short u16;
typedef __attribute__((ext_vector_type(8))) short short8;
typedef __attribute__((ext_vector_type(8))) unsigned short u16x8;
typedef __attribute__((ext_vector_type(4))) unsigned short u16x4;
typedef __attribute__((ext_vector_type(4))) float f32x4;

__device__ __forceinline__ u16 f2bf(float f) {
    uint32_t u = __float_as_uint(f);
    u += 0x7fffu + ((u >> 16) & 1u);   // RNE
    return (u16)(u >> 16);
}

__device__ __forceinline__ void gl2lds16(const void* g, void* l) {
    __builtin_amdgcn_global_load_lds(
        (const __attribute__((address_space(1))) void*)(uintptr_t)g,
        (__attribute__((address_space(3))) void*)(uint32_t)(uintptr_t)l,
        16, 0, 0);
}

#define BAR()    do { asm volatile("" ::: "memory"); __builtin_amdgcn_s_barrier(); asm volatile("" ::: "memory"); } while (0)
#define WAITV3() asm volatile("s_waitcnt vmcnt(3)" ::: "memory")
#define WAITV0() asm volatile("s_waitcnt vmcnt(0)" ::: "memory")
#define WAITL0() asm volatile("s_waitcnt lgkmcnt(0)" ::: "memory")

// ---------------- f32 -> bf16 conversion ----------------
__global__ __launch_bounds__(256) void k_convert(const float* __restrict__ src,
                                                 u16* __restrict__ dst, int n) {
    const int stride = gridDim.x * blockDim.x;
    for (int t = blockIdx.x * blockDim.x + threadIdx.x; t * 8 < n; t += stride) {
        const int i = t * 8;
        float4 a = *reinterpret_cast<const float4*>(src + i);
        float4 b = *reinterpret_cast<const float4*>(src + i + 4);
        u16x8 o;
        o[0] = f2bf(a.x); o[1] = f2bf(a.y); o[2] = f2bf(a.z); o[3] = f2bf(a.w);
        o[4] = f2bf(b.x); o[5] = f2bf(b.y); o[6] = f2bf(b.z); o[7] = f2bf(b.w);
        *reinterpret_cast<u16x8*>(dst + i) = o;
    }
}

// ---------------- Wmod[b] = W_slab + (A[idx_b] @ B[idx_b])^T, bf16 ----------------
__global__ __launch_bounds__(256) void k_build(const float* __restrict__ W,
                                               const float* __restrict__ Aq_pool,
                                               const float* __restrict__ Bq_pool,
                                               const float* __restrict__ Av_pool,
                                               const float* __restrict__ Bv_pool,
                                               const int* __restrict__ idx,
                                               u16* __restrict__ Wmq,
                                               u16* __restrict__ Wmv) {
    const int b  = blockIdx.x >> 7;
    const int s  = (blockIdx.x >> 6) & 1;
    const int og = blockIdx.x & 63;
    const int p  = idx[b];
    const float* A  = (s ? Av_pool : Aq_pool) + (size_t)p * DIM * RANK;
    const float* Bp = (s ? Bv_pool : Bq_pool) + (size_t)p * RANK * DIM;
    const float* Ws = W + (size_t)(s ? 2048 : 0) * DIM;
    u16* dst = (s ? Wmv : Wmq) + (size_t)b * DIM * DIM;

    const int t  = threadIdx.x;
    const int i0 = t * 4;
    float a[4][8];
    #pragma unroll
    for (int ii = 0; ii < 4; ++ii) {
        float4 a0 = reinterpret_cast<const float4*>(A + (size_t)(i0 + ii) * RANK)[0];
        float4 a1 = reinterpret_cast<const float4*>(A + (size_t)(i0 + ii) * RANK)[1];
        a[ii][0] = a0.x; a[ii][1] = a0.y; a[ii][2] = a0.z; a[ii][3] = a0.w;
        a[ii][4] = a1.x; a[ii][5] = a1.y; a[ii][6] = a1.z; a[ii][7] = a1.w;
    }
    for (int r = 0; r < 16; ++r) {
        const int o = og * 16 + r;
        float bv[8];
        #pragma unroll
        for (int rr = 0; rr < 8; ++rr) bv[rr] = Bp[(size_t)rr * DIM + o];
        float4 w = *reinterpret_cast<const float4*>(Ws + (size_t)o * DIM + i0);
        float v[4] = {w.x, w.y, w.z, w.w};
        u16x4 ov;
        #pragma unroll
        for (int ii = 0; ii < 4; ++ii) {
            float d = 0.f;
            #pragma unroll
            for (int rr = 0; rr < 8; ++rr) d += a[ii][rr] * bv[rr];
            ov[ii] = f2bf(v[ii] + d);
        }
        *reinterpret_cast<u16x4*>(dst + (size_t)o * DIM + i0) = ov;
    }
}

// ---------------- 128x256 8-wave triple-buffered GEMM, 2 blocks/CU ----------------
// ONLY HW-proven components, recombined:
//  - 16x16x32 MFMA + R6/R10 LDS layout & read function (measured 0-conflict 2x):
//    matrix row r, 16B k-group gk -> LDS row r>>1 (128B), slot ((r&1)*4+gk)^((r>>1)&7);
//    read: lr=l&15, kg=l>>4, axc=(lr>>1)*64 + ((((lr&1)*4)+kg)^(lr>>1))*8.
//  - R6 schedule: stage(t+2, 3 loads/wave) | 8 ds_read | lgkm0 | prio1 16 MFMA prio0 |
//    vmcnt(3) retires tile t+1 (t+2 stays in flight; never drains) | BAR.
//    Tail count-guaranteed: t=30 vmcnt(0), t=31 plain.
//  - NEW geometry only: 8 waves (2wr x 4wc, 64x64 each, acc=64 regs -> 128 total,
//    exactly the 16-wave/CU reg budget), LDS 3 x 24KB = 72KB -> 2 blocks/CU
//    (144KB LDS, launch_bounds(512,4)). Two resident blocks hide each other's
//    barrier convergence and stage latency (the m97 mechanism R9's 128KB forbade).
//  - BN=256 keeps the R9-class fetch profile (not R10's BM=BN=128 blowup).

__device__ __forceinline__ void stage(const u16* __restrict__ Xc,
                                      const u16* __restrict__ Bm,
                                      int m0, int nc, int tk,
                                      u16* buf, int wave, int lane) {
    const int q  = (lane & 7) ^ (lane >> 3);
    const int r  = (lane >> 3) * 2 + (q >> 2);      // row within 16-row slab
    const int gk = q & 3;                            // 16B k-group
    // A: wave owns 16 rows (1 load): rows wave*16..+16 -> LDS u16 [wave*512, +512)
    gl2lds16(Xc + (size_t)(m0 + wave * 16 + r) * DIM + tk + gk * 8,
             buf + wave * 512);
    // B: wave owns 32 rows (2 loads)
    gl2lds16(Bm + (size_t)(nc + wave * 32 + r) * DIM + tk + gk * 8,
             buf + 4096 + wave * 1024);
    gl2lds16(Bm + (size_t)(nc + wave * 32 + 16 + r) * DIM + tk + gk * 8,
             buf + 4096 + wave * 1024 + 512);
}

__device__ __forceinline__ void tile_mfma(const u16* __restrict__ buf,
                                          int wr, int wc, int axc,
                                          f32x4 (&acc)[4][4]) {
    short8 a[4], b[4];
    #pragma unroll
    for (int f = 0; f < 4; ++f)
        a[f] = *reinterpret_cast<const short8*>(buf + wr * 2048 + f * 512 + axc);
    #pragma unroll
    for (int n = 0; n < 4; ++n)
        b[n] = *reinterpret_cast<const short8*>(buf + 4096 + wc * 2048 + n * 512 + axc);
    WAITL0();
    __builtin_amdgcn_s_setprio(1);
    #pragma unroll
    for (int f = 0; f < 4; ++f)
        #pragma unroll
        for (int n = 0; n < 4; ++n)
            acc[f][n] = __builtin_amdgcn_mfma_f32_16x16x32_bf16(a[f], b[n], acc[f][n], 0, 0, 0);
    __builtin_amdgcn_s_setprio(0);
}

__global__ __launch_bounds__(512, 4) void k_gemm(const u16* __restrict__ Xc,
                                                 const u16* __restrict__ Wk,
                                                 const u16* __restrict__ Wmq,
                                                 const u16* __restrict__ Wmv,
                                                 const float* __restrict__ bias,
                                                 float* __restrict__ out) {
    extern __shared__ u16 lds[];               // 72 KiB: 3 x 12288 u16
    const int tid  = threadIdx.x;
    const int lane = tid & 63, wave = tid >> 6;
    const int wr = wave >> 2, wc = wave & 3;   // 2M x 4N wave grid, 64x64 each

    // bijective XCD swizzle (nwg=3072, 3072%8==0)
    const int orig = blockIdx.x;
    const int wg   = (orig & 7) * 384 + (orig >> 3);
    const int bn   = wg % 12;
    const int bm   = wg / 12;
    const int m0 = bm * 128, n0 = bn * 256;
    const int batch = m0 >> 12;

    const u16* Bmat;
    int nc;
    if (n0 < DIM)           { Bmat = Wmq + (size_t)batch * DIM * DIM; nc = n0; }
    else if (n0 < 2 * DIM)  { Bmat = Wk;                              nc = n0 - DIM; }
    else                    { Bmat = Wmv + (size_t)batch * DIM * DIM; nc = n0 - 2 * DIM; }

    // R6-proven per-lane read offset
    const int lr  = lane & 15;
    const int axc = (lr >> 1) * 64 + ((((lr & 1) * 4) + (lane >> 4)) ^ (lr >> 1)) * 8;

    u16* p0 = lds;
    u16* p1 = lds + 12288;
    u16* p2 = lds + 24576;

    f32x4 acc[4][4] = {};

    // prologue: stage tiles 0,1; retire tile 0 by count
    stage(Xc, Bmat, m0, nc, 0,  p0, wave, lane);
    stage(Xc, Bmat, m0, nc, BK, p1, wave, lane);
    WAITV3(); BAR();

    #pragma unroll 1
    for (int t3 = 0; t3 < 30; t3 += 3) {
        stage(Xc, Bmat, m0, nc, (t3 + 2) * BK, p2, wave, lane);
        tile_mfma(p0, wr, wc, axc, acc);
        WAITV3(); BAR();               // retire tile t3+1 (read next iter)

        stage(Xc, Bmat, m0, nc, (t3 + 3) * BK, p0, wave, lane);
        tile_mfma(p1, wr, wc, axc, acc);
        WAITV3(); BAR();

        stage(Xc, Bmat, m0, nc, (t3 + 4) * BK, p1, wave, lane);
        tile_mfma(p2, wr, wc, axc, acc);
        WAITV3(); BAR();
    }
    // t = 30: read p0, no stage; drain tile 31's loads by count
    tile_mfma(p0, wr, wc, axc, acc);
    WAITV0(); BAR();
    // t = 31: read p1
    tile_mfma(p1, wr, wc, axc, acc);

    // ---------------- epilogue: bias + store ----------------
    const int cn = wc * 64 + (lane & 15);
    float bcol[4];
    #pragma unroll
    for (int n = 0; n < 4; ++n) bcol[n] = bias[n0 + cn + n * 16];
    #pragma unroll
    for (int f = 0; f < 4; ++f) {
        const int rb = m0 + wr * 64 + f * 16 + (lane >> 4) * 4;
        #pragma unroll
        for (int v = 0; v < 4; ++v) {
            const size_t row = (size_t)(rb + v);
            #pragma unroll
            for (int n = 0; n < 4; ++n)
                out[row * ODIM + (size_t)(n0 + cn + n * 16)] = acc[f][n][v] + bcol[n];
        }
    }
}

extern "C" void kernel_launch(void* const* d_in, const int* in_sizes, int n_in,
                              void* d_out, int out_size, void* d_ws, size_t ws_size,
                              hipStream_t stream) {
    const float* x      = (const float*)d_in[0];
    const float* weight = (const float*)d_in[1];
    const float* bias   = (const float*)d_in[2];
    const float* Aq     = (const float*)d_in[3];
    const float* Bq     = (const float*)d_in[4];
    const float* Av     = (const float*)d_in[5];
    const float* Bv     = (const float*)d_in[6];
    const int*   idx    = (const int*)d_in[7];
    float* out = (float*)d_out;

    // workspace: Xc(64MB) | Wk(2MB) | Wmq(16MB) | Wmv(16MB) = 98MB
    u16* Xc  = (u16*)d_ws;
    u16* Wk  = Xc + (size_t)MROWS * DIM;
    u16* Wmq = Wk + (size_t)DIM * DIM;
    u16* Wmv = Wmq + (size_t)8 * DIM * DIM;

    hipFuncSetAttribute(reinterpret_cast<const void*>(k_gemm),
                        hipFuncAttributeMaxDynamicSharedMemorySize, 73728);

    k_convert<<<2048, 256, 0, stream>>>(x, Xc, MROWS * DIM);
    k_convert<<<512, 256, 0, stream>>>(weight + (size_t)DIM * DIM, Wk, DIM * DIM);
    k_build<<<1024, 256, 0, stream>>>(weight, Aq, Bq, Av, Bv, idx, Wmq, Wmv);
    k_gemm<<<3072, 512, 73728, stream>>>(Xc, Wk, Wmq, Wmv, bias, out);
}